// Round 7
// baseline (216.263 us; speedup 1.0000x reference)
//
#include <hip/hip_runtime.h>
#include <hip/hip_cooperative_groups.h>

namespace cg = cooperative_groups;

// ---------------------------------------------------------------------------
// LoRA_Attention, single cooperative kernel: phase0 convert+fold, phase1 QKV
// GEMM (global_load_lds DMA), phase2 rel-pos MFMA GEMMs, phase3 split-K flash
// attention (S^T core, registerized relW, 38.4 KB LDS), phase4 merge, phase5
// output projection. grid.sync() between phases replaces kernel launches.
// Fallback: R6's 7-kernel path if cooperative launch is unsupported.
// ---------------------------------------------------------------------------

#define DIM   768
#define HEADS 12
#define HD    64
#define NTOK  2304
#define RANK  8
#define GRD   48
#define CHUNKS 4
#define LOG2E 1.44269504088896f
#define NBLK  768

typedef __attribute__((ext_vector_type(8))) short bf16x8;
typedef __attribute__((ext_vector_type(4))) float f32x4;
typedef unsigned short ushort_t;

__device__ __forceinline__ unsigned short f2bf(float x) {
    union { float f; unsigned u; } v; v.f = x;
    unsigned r = v.u + 0x7fffu + ((v.u >> 16) & 1u);
    return (unsigned short)(r >> 16);
}
__device__ __forceinline__ float bf2f(unsigned short h) {
    return __uint_as_float(((unsigned)h) << 16);
}
__device__ __forceinline__ void gload_lds16(const ushort_t* g, ushort_t* l) {
    __builtin_amdgcn_global_load_lds(
        (const __attribute__((address_space(1))) unsigned int*)g,
        (__attribute__((address_space(3))) unsigned int*)l, 16, 0, 0);
}

struct MonoP {
    const float *x, *Wq, *bq, *Wk, *bk, *Wv, *bv, *Wp, *bp, *rph, *rpw,
                *Aq, *Bq, *Ak, *Bk, *Av, *Bv;
    float *out;
    ushort_t *xb, *WT, *Qb, *Kb, *Vtb, *Ob, *rphb, *rpwb;
    float *relH, *relW, *Opart, *Lpart;
};

// ===========================================================================
// Monolithic cooperative kernel
// ===========================================================================
__global__ __launch_bounds__(256, 4) void k_mono(MonoP P) {
    cg::grid_group gg = cg::this_grid();
    __shared__ __align__(16) unsigned char smem[38912];
    const int bid = blockIdx.x, tid = threadIdx.x;
    const int wave = tid >> 6, lane = tid & 63, quad = lane >> 4, l16 = lane & 15;
    const f32x4 zero = {0.f, 0.f, 0.f, 0.f};

    // ---- phase 0a: convert x + rel tables to bf16 -------------------------
    for (int ct = bid; ct < 1740; ct += NBLK) {
        if (ct < 1728) {
            int idx = (ct * 256 + tid) * 4;
            float4 v = *(const float4*)(P.x + idx);
            ushort4 o = make_ushort4(f2bf(v.x), f2bf(v.y), f2bf(v.z), f2bf(v.w));
            *(ushort4*)(P.xb + idx) = o;
        } else {
            int e = ((ct - 1728) * 256 + tid) * 4;
            const int TSZ = (2 * GRD - 1) * HD;   // 6080
            if (e < TSZ) {
                float4 v = *(const float4*)(P.rph + e);
                ushort4 o = make_ushort4(f2bf(v.x), f2bf(v.y), f2bf(v.z), f2bf(v.w));
                *(ushort4*)(P.rphb + e) = o;
            } else if (e < 2 * TSZ) {
                float4 v = *(const float4*)(P.rpw + e - TSZ);
                ushort4 o = make_ushort4(f2bf(v.x), f2bf(v.y), f2bf(v.z), f2bf(v.w));
                *(ushort4*)(P.rpwb + e - TSZ) = o;
            }
        }
    }
    // ---- phase 0b: fold LoRA into transposed weights ----------------------
    {
        float* T = (float*)smem;               // [32][33]
        for (int ft = bid; ft < 2304; ft += NBLK) {   // 2304 = 3*NBLK, uniform
            int kb = (ft % 24) * 32, nb = (ft / 24) * 32;
            int sel = nb / DIM, nmod = nb % DIM;
            const float* W = (sel == 0) ? P.Wq : (sel == 1) ? P.Wk : (sel == 2) ? P.Wv : P.Wp;
            const float* A = (sel == 0) ? P.Aq : (sel == 1) ? P.Ak : P.Av;
            const float* B = (sel == 0) ? P.Bq : (sel == 1) ? P.Bk : P.Bv;
            for (int i = tid; i < 1024; i += 256) {
                int kl = i >> 5, nl = i & 31;
                float v = W[(kb + kl) * DIM + nmod + nl];
                if (sel < 3) {
                    #pragma unroll
                    for (int r = 0; r < RANK; r++)
                        v += A[(kb + kl) * RANK + r] * B[r * DIM + nmod + nl];
                }
                T[kl * 33 + nl] = v;
            }
            __syncthreads();
            for (int i = tid; i < 1024; i += 256) {
                int nl = i >> 5, kl = i & 31;
                P.WT[(size_t)(nb + nl) * DIM + kb + kl] = f2bf(T[kl * 33 + nl]);
            }
            __syncthreads();
        }
    }
    gg.sync();

    // ---- phase 1: QKV GEMM (blocks 0..323) --------------------------------
    if (bid < 324) {
        ushort_t* As = (ushort_t*)smem;
        ushort_t* Bs = (ushort_t*)(smem + 8192);
        int wx = wave & 1, wy = wave >> 1;
        int nb = (bid % 18) * 128, mb = (bid / 18) * 128;

        f32x4 acc[4][4];
        #pragma unroll
        for (int i = 0; i < 4; i++)
            #pragma unroll
            for (int j = 0; j < 4; j++) acc[i][j] = zero;

        int rl = lane >> 2, cl = (lane & 3) * 8;
        const ushort_t* gA = P.xb + (size_t)(mb + wave * 32 + rl) * DIM + cl;
        const ushort_t* gB = P.WT + (size_t)(nb + wave * 32 + rl) * DIM + cl;
        ushort_t* lA = &As[(wave * 32) * 32];
        ushort_t* lB = &Bs[(wave * 32) * 32];

        for (int k0 = 0; k0 < DIM; k0 += 32) {
            __syncthreads();
            gload_lds16(gA + k0,            lA);
            gload_lds16(gA + k0 + 16 * DIM, lA + 16 * 32);
            gload_lds16(gB + k0,            lB);
            gload_lds16(gB + k0 + 16 * DIM, lB + 16 * 32);
            __syncthreads();
            bf16x8 af[4], bf[4];
            #pragma unroll
            for (int i = 0; i < 4; i++)
                af[i] = *(const bf16x8*)&As[(wy * 64 + i * 16 + l16) * 32 + quad * 8];
            #pragma unroll
            for (int j = 0; j < 4; j++)
                bf[j] = *(const bf16x8*)&Bs[(wx * 64 + j * 16 + l16) * 32 + quad * 8];
            #pragma unroll
            for (int i = 0; i < 4; i++)
                #pragma unroll
                for (int j = 0; j < 4; j++)
                    acc[i][j] = __builtin_amdgcn_mfma_f32_16x16x32_bf16(af[i], bf[j], acc[i][j], 0, 0, 0);
        }

        #pragma unroll
        for (int j = 0; j < 4; j++) {
            int col = nb + wx * 64 + j * 16 + l16;
            int sel = col / DIM, rem = col % DIM;
            int hh = rem >> 6, cc = rem & 63;
            const float* bias = (sel == 0) ? P.bq : (sel == 1) ? P.bk : P.bv;
            float bval = bias[rem];
            #pragma unroll
            for (int i = 0; i < 4; i++) {
                #pragma unroll
                for (int r = 0; r < 4; r++) {
                    int row = mb + wy * 64 + i * 16 + quad * 4 + r;
                    unsigned short o = f2bf(acc[i][j][r] + bval);
                    if (sel == 0)      P.Qb[(size_t)(hh * NTOK + row) * HD + cc] = o;
                    else if (sel == 1) P.Kb[(size_t)(hh * NTOK + row) * HD + cc] = o;
                    else               P.Vtb[(size_t)(hh * HD + cc) * NTOK + row] = o;
                }
            }
        }
    }
    gg.sync();

    // ---- phase 2: rel-pos bias via MFMA (blocks 0..287) -------------------
    if (bid < 288) {
        int id = bid * 4 + wave;
        bool isW = id >= 576;
        int t = isW ? id - 576 : id;
        int h = t / GRD, g = t % GRD;
        const ushort_t* tab = isW ? P.rpwb : P.rphb;
        float* outp = isW ? P.relW : P.relH;

        f32x4 acc[3][3];
        #pragma unroll
        for (int i = 0; i < 3; i++)
            #pragma unroll
            for (int j = 0; j < 3; j++) acc[i][j] = zero;

        bf16x8 bfr[3][2];
        #pragma unroll
        for (int ct = 0; ct < 3; ct++) {
            int trow = g + 47 - (ct * 16 + l16);
            bfr[ct][0] = *(const bf16x8*)&tab[(size_t)trow * HD + quad * 8];
            bfr[ct][1] = *(const bf16x8*)&tab[(size_t)trow * HD + 32 + quad * 8];
        }
        #pragma unroll
        for (int ms = 0; ms < 3; ms++) {
            int m = ms * 16 + l16;
            int n = isW ? m * GRD + g : g * GRD + m;
            bf16x8 a0 = *(const bf16x8*)&P.Qb[(size_t)(h * NTOK + n) * HD + quad * 8];
            bf16x8 a1 = *(const bf16x8*)&P.Qb[(size_t)(h * NTOK + n) * HD + 32 + quad * 8];
            #pragma unroll
            for (int ct = 0; ct < 3; ct++) {
                acc[ms][ct] = __builtin_amdgcn_mfma_f32_16x16x32_bf16(a0, bfr[ct][0], acc[ms][ct], 0, 0, 0);
                acc[ms][ct] = __builtin_amdgcn_mfma_f32_16x16x32_bf16(a1, bfr[ct][1], acc[ms][ct], 0, 0, 0);
            }
        }
        #pragma unroll
        for (int ms = 0; ms < 3; ms++) {
            #pragma unroll
            for (int ct = 0; ct < 3; ct++) {
                #pragma unroll
                for (int r = 0; r < 4; r++) {
                    int m = ms * 16 + quad * 4 + r;
                    int n = isW ? m * GRD + g : g * GRD + m;
                    int col = ct * 16 + l16;
                    outp[(size_t)(h * NTOK + n) * GRD + col] = acc[ms][ct][r] * LOG2E;
                }
            }
        }
    }
    gg.sync();

    // ---- phase 3: flash attention, 864 tiles over 768 blocks --------------
    for (int tile = bid; tile < 864; tile += NBLK) {
        int xx = tile % 48, qt = tile / 48;      // xx = h*4+chunk (XCD-local)
        int h = xx >> 2, chunk = xx & 3;
        int qbase = qt * 128, kbase = chunk * 576;

        ushort_t* Ks  = (ushort_t*)smem;                              //  8704 B
        ushort_t* Vs  = (ushort_t*)(smem + 8704);                     //  8704 B
        ushort_t* Psw = (ushort_t*)(smem + 17408) + wave * (32 * 68); // 17408 B
        ushort_t* rhs = (ushort_t*)(smem + 34816);                    //  3584 B

        __syncthreads();   // smem reuse across phases/tiles

        // stage rel_h (12 kh of this chunk), bf16, stride 14
        for (int i = tid; i < 128 * 12; i += 256) {
            int r = i / 12, c = i % 12;
            rhs[r * 14 + c] = f2bf(P.relH[(size_t)(h * NTOK + qbase + r) * GRD + chunk * 12 + c]);
        }

        // Q B-fragments (wave owns 32 rows = 2 strips)
        bf16x8 qf[2][2];
        #pragma unroll
        for (int s = 0; s < 2; s++) {
            int qrow = qbase + wave * 32 + s * 16 + l16;
            qf[s][0] = *(const bf16x8*)&P.Qb[(size_t)(h * NTOK + qrow) * HD + quad * 8];
            qf[s][1] = *(const bf16x8*)&P.Qb[(size_t)(h * NTOK + qrow) * HD + 32 + quad * 8];
        }
        // registerized relW: kw0 = 16*((kt+ks)%3) + 4*quad -> 3 uint2/strip
        uint2 rwreg[2][3];
        #pragma unroll
        for (int s = 0; s < 2; s++) {
            int row = qbase + wave * 32 + s * 16 + l16;
            const float* rp = P.relW + (size_t)(h * NTOK + row) * GRD + quad * 4;
            #pragma unroll
            for (int m3 = 0; m3 < 3; m3++) {
                float4 rw = *(const float4*)(rp + m3 * 16);
                uint2 u;
                u.x = (unsigned)f2bf(rw.x) | ((unsigned)f2bf(rw.y) << 16);
                u.y = (unsigned)f2bf(rw.z) | ((unsigned)f2bf(rw.w) << 16);
                rwreg[s][m3] = u;
            }
        }

        int r0 = tid >> 3, c0 = (tid & 7) * 8;
        const ushort_t* kg0 = P.Kb + (size_t)(h * NTOK + r0) * HD + c0;
        const ushort_t* kg1 = P.Kb + (size_t)(h * NTOK + r0 + 32) * HD + c0;
        const ushort_t* vg0 = P.Vtb + (size_t)(h * HD + r0) * NTOK + c0;
        const ushort_t* vg1 = P.Vtb + (size_t)(h * HD + r0 + 32) * NTOK + c0;
        int sk0 = r0 * 68 + c0, sk1 = sk0 + 32 * 68;

        float lacc[2] = {0.f, 0.f};
        f32x4 oacc[2][4];
        #pragma unroll
        for (int s = 0; s < 2; s++)
            #pragma unroll
            for (int cs = 0; cs < 4; cs++) oacc[s][cs] = zero;

        const float scale2 = 0.125f * LOG2E;

        uint4 rk0 = *(const uint4*)(kg0 + (size_t)kbase * HD);
        uint4 rk1 = *(const uint4*)(kg1 + (size_t)kbase * HD);
        uint4 rv0 = *(const uint4*)(vg0 + kbase);
        uint4 rv1 = *(const uint4*)(vg1 + kbase);

        for (int kt = 0; kt < 9; kt++) {
            int kb = kbase + kt * 64;
            __syncthreads();
            *(uint4*)&Ks[sk0] = rk0;  *(uint4*)&Ks[sk1] = rk1;
            *(uint4*)&Vs[sk0] = rv0;  *(uint4*)&Vs[sk1] = rv1;
            __syncthreads();
            if (kt < 8) {
                int kbn = kb + 64;
                rk0 = *(const uint4*)(kg0 + (size_t)kbn * HD);
                rk1 = *(const uint4*)(kg1 + (size_t)kbn * HD);
                rv0 = *(const uint4*)(vg0 + kbn);
                rv1 = *(const uint4*)(vg1 + kbn);
            }

            #pragma unroll
            for (int ks = 0; ks < 4; ks++) {
                bf16x8 kf0 = *(const bf16x8*)&Ks[(ks * 16 + l16) * 68 + quad * 8];
                bf16x8 kf1 = *(const bf16x8*)&Ks[(ks * 16 + l16) * 68 + 32 + quad * 8];
                f32x4 st[2];
                #pragma unroll
                for (int s = 0; s < 2; s++) {
                    f32x4 z = zero;
                    z = __builtin_amdgcn_mfma_f32_16x16x32_bf16(kf0, qf[s][0], z, 0, 0, 0);
                    z = __builtin_amdgcn_mfma_f32_16x16x32_bf16(kf1, qf[s][1], z, 0, 0, 0);
                    st[s] = z;
                }
                int kb4 = kb + ks * 16 + quad * 4;
                int khl = kb4 / 48 - chunk * 12;      // uniform per quad
                int m3 = (kt + ks) % 3;               // lane-uniform
                #pragma unroll
                for (int s = 0; s < 2; s++) {
                    int row = wave * 32 + s * 16 + l16;
                    float rh = bf2f(rhs[row * 14 + khl]);
                    uint2 u = (m3 == 0) ? rwreg[s][0] : (m3 == 1) ? rwreg[s][1] : rwreg[s][2];
                    float p0 = __builtin_amdgcn_exp2f(st[s][0] * scale2 + rh + __uint_as_float(u.x << 16));
                    float p1 = __builtin_amdgcn_exp2f(st[s][1] * scale2 + rh + __uint_as_float(u.x & 0xffff0000u));
                    float p2 = __builtin_amdgcn_exp2f(st[s][2] * scale2 + rh + __uint_as_float(u.y << 16));
                    float p3 = __builtin_amdgcn_exp2f(st[s][3] * scale2 + rh + __uint_as_float(u.y & 0xffff0000u));
                    lacc[s] += (p0 + p1) + (p2 + p3);
                    uint2 w;
                    w.x = __builtin_amdgcn_perm(__float_as_uint(p1), __float_as_uint(p0), 0x07060302u);
                    w.y = __builtin_amdgcn_perm(__float_as_uint(p3), __float_as_uint(p2), 0x07060302u);
                    *(uint2*)&Psw[(s * 16 + l16) * 68 + ks * 16 + quad * 4] = w;
                }
            }

            bf16x8 vf[4][2];
            #pragma unroll
            for (int cs = 0; cs < 4; cs++) {
                vf[cs][0] = *(const bf16x8*)&Vs[(cs * 16 + l16) * 68 + quad * 8];
                vf[cs][1] = *(const bf16x8*)&Vs[(cs * 16 + l16) * 68 + 32 + quad * 8];
            }
            #pragma unroll
            for (int s = 0; s < 2; s++) {
                bf16x8 pa0 = *(const bf16x8*)&Psw[(s * 16 + l16) * 68 + quad * 8];
                bf16x8 pa1 = *(const bf16x8*)&Psw[(s * 16 + l16) * 68 + 32 + quad * 8];
                #pragma unroll
                for (int cs = 0; cs < 4; cs++) {
                    oacc[s][cs] = __builtin_amdgcn_mfma_f32_16x16x32_bf16(pa0, vf[cs][0], oacc[s][cs], 0, 0, 0);
                    oacc[s][cs] = __builtin_amdgcn_mfma_f32_16x16x32_bf16(pa1, vf[cs][1], oacc[s][cs], 0, 0, 0);
                }
            }
        }

        #pragma unroll
        for (int s = 0; s < 2; s++) {
            float l = lacc[s];
            l += __shfl_xor(l, 16);
            l += __shfl_xor(l, 32);
            lacc[s] = l;
        }

        size_t obase = (size_t)(chunk * HEADS + h) * NTOK;
        #pragma unroll
        for (int s = 0; s < 2; s++) {
            #pragma unroll
            for (int cs = 0; cs < 4; cs++) {
                #pragma unroll
                for (int r = 0; r < 4; r++) {
                    int row = qbase + wave * 32 + s * 16 + quad * 4 + r;
                    P.Opart[(obase + row) * HD + cs * 16 + l16] = oacc[s][cs][r];
                }
            }
            if (quad == 0)
                P.Lpart[obase + qbase + wave * 32 + s * 16 + l16] = lacc[s];
        }
    }
    gg.sync();

    // ---- phase 4: merge split-K partials ----------------------------------
    for (int mt = bid; mt < 1728; mt += NBLK) {
        int t = mt * 256 + tid;
        int e = t * 4;
        int c = e & (HD - 1);
        int row = (e >> 6) % NTOK;
        int h = e / (NTOK * HD);
        const int ostride = HEADS * NTOK * HD;
        float4 s4 = {0.f, 0.f, 0.f, 0.f};
        float l = 0.f;
        #pragma unroll
        for (int ch = 0; ch < CHUNKS; ch++) {
            float4 v = *(const float4*)&P.Opart[(size_t)ch * ostride + e];
            s4.x += v.x; s4.y += v.y; s4.z += v.z; s4.w += v.w;
            l += P.Lpart[(size_t)(ch * HEADS + h) * NTOK + row];
        }
        float inv = 1.0f / l;
        ushort4 o = make_ushort4(f2bf(s4.x * inv), f2bf(s4.y * inv),
                                 f2bf(s4.z * inv), f2bf(s4.w * inv));
        *(ushort4*)&P.Ob[(size_t)row * DIM + h * HD + c] = o;
    }
    gg.sync();

    // ---- phase 5: output projection (blocks 0..107) -----------------------
    if (bid < 108) {
        ushort_t* As = (ushort_t*)smem;
        ushort_t* Bs = (ushort_t*)(smem + 10240);
        int wx = wave & 1, wy = wave >> 1;
        int nb = (bid % 6) * 128, mb = (bid / 6) * 128;
        const ushort_t* WTp = P.WT + (size_t)3 * DIM * DIM;

        f32x4 acc[4][4];
        #pragma unroll
        for (int i = 0; i < 4; i++)
            #pragma unroll
            for (int j = 0; j < 4; j++) acc[i][j] = zero;

        const ushort_t* Ag = P.Ob + (size_t)(mb + (tid >> 1)) * DIM + (tid & 1) * 16;
        const ushort_t* Bg = WTp + (size_t)(nb + (tid >> 1)) * DIM + (tid & 1) * 16;
        int sidx = (tid >> 1) * 40 + (tid & 1) * 16;

        for (int k0 = 0; k0 < DIM; k0 += 32) {
            uint4 a0 = *(const uint4*)(Ag + k0);
            uint4 a1 = *(const uint4*)(Ag + k0 + 8);
            uint4 b0 = *(const uint4*)(Bg + k0);
            uint4 b1 = *(const uint4*)(Bg + k0 + 8);
            __syncthreads();
            *(uint4*)&As[sidx] = a0;  *(uint4*)&As[sidx + 8] = a1;
            *(uint4*)&Bs[sidx] = b0;  *(uint4*)&Bs[sidx + 8] = b1;
            __syncthreads();
            bf16x8 af[4], bf[4];
            #pragma unroll
            for (int i = 0; i < 4; i++)
                af[i] = *(const bf16x8*)&As[(wy * 64 + i * 16 + l16) * 40 + quad * 8];
            #pragma unroll
            for (int j = 0; j < 4; j++)
                bf[j] = *(const bf16x8*)&Bs[(wx * 64 + j * 16 + l16) * 40 + quad * 8];
            #pragma unroll
            for (int i = 0; i < 4; i++)
                #pragma unroll
                for (int j = 0; j < 4; j++)
                    acc[i][j] = __builtin_amdgcn_mfma_f32_16x16x32_bf16(af[i], bf[j], acc[i][j], 0, 0, 0);
        }

        #pragma unroll
        for (int j = 0; j < 4; j++) {
            int col = nb + wx * 64 + j * 16 + l16;
            float bval = P.bp[col];
            #pragma unroll
            for (int i = 0; i < 4; i++) {
                #pragma unroll
                for (int r = 0; r < 4; r++) {
                    int row = mb + wy * 64 + i * 16 + quad * 4 + r;
                    P.out[(size_t)row * DIM + col] = acc[i][j][r] + bval;
                }
            }
        }
    }
}

// ===========================================================================
// Fallback kernels (R6 path, proven at 213.6 us)
// ===========================================================================
__global__ __launch_bounds__(256) void k_convert_x(
    const float* __restrict__ x, ushort_t* __restrict__ xb,
    const float* __restrict__ rph, const float* __restrict__ rpw,
    ushort_t* __restrict__ rphb, ushort_t* __restrict__ rpwb) {
    if (blockIdx.x < 1728) {
        int idx = (blockIdx.x * 256 + threadIdx.x) * 4;
        float4 v = *(const float4*)(x + idx);
        ushort4 o = make_ushort4(f2bf(v.x), f2bf(v.y), f2bf(v.z), f2bf(v.w));
        *(ushort4*)(xb + idx) = o;
    } else {
        int e = ((blockIdx.x - 1728) * 256 + threadIdx.x) * 4;
        const int TSZ = (2 * GRD - 1) * HD;
        if (e < TSZ) {
            float4 v = *(const float4*)(rph + e);
            ushort4 o = make_ushort4(f2bf(v.x), f2bf(v.y), f2bf(v.z), f2bf(v.w));
            *(ushort4*)(rphb + e) = o;
        } else if (e < 2 * TSZ) {
            float4 v = *(const float4*)(rpw + e - TSZ);
            ushort4 o = make_ushort4(f2bf(v.x), f2bf(v.y), f2bf(v.z), f2bf(v.w));
            *(ushort4*)(rpwb + e - TSZ) = o;
        }
    }
}

__global__ __launch_bounds__(256) void k_fold(
    const float* __restrict__ Wq, const float* __restrict__ Wk,
    const float* __restrict__ Wv, const float* __restrict__ Wp,
    const float* __restrict__ Aq, const float* __restrict__ Bq,
    const float* __restrict__ Ak, const float* __restrict__ Bk,
    const float* __restrict__ Av, const float* __restrict__ Bv,
    ushort_t* __restrict__ WT) {
    int kb = blockIdx.x * 32;
    int nb = blockIdx.y * 32;
    int sel = nb / DIM, nmod = nb % DIM;
    const float* W = (sel == 0) ? Wq : (sel == 1) ? Wk : (sel == 2) ? Wv : Wp;
    const float* A = (sel == 0) ? Aq : (sel == 1) ? Ak : Av;
    const float* B = (sel == 0) ? Bq : (sel == 1) ? Bk : Bv;
    __shared__ float T[32][33];
    for (int i = threadIdx.x; i < 1024; i += 256) {
        int kl = i / 32, nl = i % 32;
        float v = W[(kb + kl) * DIM + nmod + nl];
        if (sel < 3) {
            #pragma unroll
            for (int r = 0; r < RANK; r++)
                v += A[(kb + kl) * RANK + r] * B[r * DIM + nmod + nl];
        }
        T[kl][nl] = v;
    }
    __syncthreads();
    for (int i = threadIdx.x; i < 1024; i += 256) {
        int nl = i / 32, kl = i % 32;
        WT[(size_t)(nb + nl) * DIM + kb + kl] = f2bf(T[kl][nl]);
    }
}

__global__ __launch_bounds__(256) void k_gemm_qkv(
    const ushort_t* __restrict__ xb, const ushort_t* __restrict__ WT,
    const float* __restrict__ bq, const float* __restrict__ bk,
    const float* __restrict__ bv,
    ushort_t* __restrict__ Qb, ushort_t* __restrict__ Kb,
    ushort_t* __restrict__ Vtb) {
    __shared__ __align__(16) ushort_t As[128 * 32];
    __shared__ __align__(16) ushort_t Bs[128 * 32];
    int tid = threadIdx.x;
    int wave = tid >> 6, lane = tid & 63, quad = lane >> 4, l16 = lane & 15;
    int wx = wave & 1, wy = wave >> 1;
    int nb = blockIdx.x * 128, mb = blockIdx.y * 128;
    f32x4 zero = {0.f, 0.f, 0.f, 0.f};
    f32x4 acc[4][4];
    #pragma unroll
    for (int i = 0; i < 4; i++)
        #pragma unroll
        for (int j = 0; j < 4; j++) acc[i][j] = zero;
    int rl = lane >> 2, cl = (lane & 3) * 8;
    const ushort_t* gA = xb + (size_t)(mb + wave * 32 + rl) * DIM + cl;
    const ushort_t* gB = WT + (size_t)(nb + wave * 32 + rl) * DIM + cl;
    ushort_t* lA = &As[(wave * 32) * 32];
    ushort_t* lB = &Bs[(wave * 32) * 32];
    for (int k0 = 0; k0 < DIM; k0 += 32) {
        __syncthreads();
        gload_lds16(gA + k0,            lA);
        gload_lds16(gA + k0 + 16 * DIM, lA + 16 * 32);
        gload_lds16(gB + k0,            lB);
        gload_lds16(gB + k0 + 16 * DIM, lB + 16 * 32);
        __syncthreads();
        bf16x8 af[4], bf[4];
        #pragma unroll
        for (int i = 0; i < 4; i++)
            af[i] = *(const bf16x8*)&As[(wy * 64 + i * 16 + l16) * 32 + quad * 8];
        #pragma unroll
        for (int j = 0; j < 4; j++)
            bf[j] = *(const bf16x8*)&Bs[(wx * 64 + j * 16 + l16) * 32 + quad * 8];
        #pragma unroll
        for (int i = 0; i < 4; i++)
            #pragma unroll
            for (int j = 0; j < 4; j++)
                acc[i][j] = __builtin_amdgcn_mfma_f32_16x16x32_bf16(af[i], bf[j], acc[i][j], 0, 0, 0);
    }
    #pragma unroll
    for (int j = 0; j < 4; j++) {
        int col = nb + wx * 64 + j * 16 + l16;
        int sel = col / DIM, rem = col % DIM;
        int hh = rem >> 6, cc = rem & 63;
        const float* bias = (sel == 0) ? bq : (sel == 1) ? bk : bv;
        float bval = bias[rem];
        #pragma unroll
        for (int i = 0; i < 4; i++) {
            #pragma unroll
            for (int r = 0; r < 4; r++) {
                int row = mb + wy * 64 + i * 16 + quad * 4 + r;
                unsigned short o = f2bf(acc[i][j][r] + bval);
                if (sel == 0)      Qb[(size_t)(hh * NTOK + row) * HD + cc] = o;
                else if (sel == 1) Kb[(size_t)(hh * NTOK + row) * HD + cc] = o;
                else               Vtb[(size_t)(hh * HD + cc) * NTOK + row] = o;
            }
        }
    }
}

__global__ __launch_bounds__(256) void k_relmm(
    const ushort_t* __restrict__ Qb, const ushort_t* __restrict__ rphb,
    const ushort_t* __restrict__ rpwb, float* __restrict__ relH,
    float* __restrict__ relW) {
    int id = blockIdx.x * 4 + (threadIdx.x >> 6);
    int lane = threadIdx.x & 63, quad = lane >> 4, l16 = lane & 15;
    bool isW = id >= 576;
    int t = isW ? id - 576 : id;
    int h = t / GRD, g = t % GRD;
    const ushort_t* tab = isW ? rpwb : rphb;
    float* outp = isW ? relW : relH;
    f32x4 zero = {0.f, 0.f, 0.f, 0.f};
    f32x4 acc[3][3];
    #pragma unroll
    for (int i = 0; i < 3; i++)
        #pragma unroll
        for (int j = 0; j < 3; j++) acc[i][j] = zero;
    bf16x8 bfr[3][2];
    #pragma unroll
    for (int ct = 0; ct < 3; ct++) {
        int trow = g + 47 - (ct * 16 + l16);
        bfr[ct][0] = *(const bf16x8*)&tab[(size_t)trow * HD + quad * 8];
        bfr[ct][1] = *(const bf16x8*)&tab[(size_t)trow * HD + 32 + quad * 8];
    }
    #pragma unroll
    for (int ms = 0; ms < 3; ms++) {
        int m = ms * 16 + l16;
        int n = isW ? m * GRD + g : g * GRD + m;
        bf16x8 a0 = *(const bf16x8*)&Qb[(size_t)(h * NTOK + n) * HD + quad * 8];
        bf16x8 a1 = *(const bf16x8*)&Qb[(size_t)(h * NTOK + n) * HD + 32 + quad * 8];
        #pragma unroll
        for (int ct = 0; ct < 3; ct++) {
            acc[ms][ct] = __builtin_amdgcn_mfma_f32_16x16x32_bf16(a0, bfr[ct][0], acc[ms][ct], 0, 0, 0);
            acc[ms][ct] = __builtin_amdgcn_mfma_f32_16x16x32_bf16(a1, bfr[ct][1], acc[ms][ct], 0, 0, 0);
        }
    }
    #pragma unroll
    for (int ms = 0; ms < 3; ms++) {
        #pragma unroll
        for (int ct = 0; ct < 3; ct++) {
            #pragma unroll
            for (int r = 0; r < 4; r++) {
                int m = ms * 16 + quad * 4 + r;
                int n = isW ? m * GRD + g : g * GRD + m;
                int col = ct * 16 + l16;
                outp[(size_t)(h * NTOK + n) * GRD + col] = acc[ms][ct][r] * LOG2E;
            }
        }
    }
}

__global__ __launch_bounds__(256) void k_attn(
    const ushort_t* __restrict__ Qb, const ushort_t* __restrict__ Kb,
    const ushort_t* __restrict__ Vtb, const float* __restrict__ relH,
    const float* __restrict__ relW, float* __restrict__ Opart,
    float* __restrict__ Lpart) {
    int h = blockIdx.x >> 2, chunk = blockIdx.x & 3, qt = blockIdx.y;
    int tid = threadIdx.x;
    int wave = tid >> 6, lane = tid & 63, quad = lane >> 4, l16 = lane & 15;
    int qbase = qt * 128;
    int kbase = chunk * 576;
    __shared__ __align__(16) ushort_t Ks[64 * 68];
    __shared__ __align__(16) ushort_t Vs[64 * 68];
    __shared__ __align__(16) ushort_t Ps[4][32 * 68];
    __shared__ __align__(16) ushort_t rws[128 * 52];
    __shared__ __align__(16) ushort_t rhs[128 * 14];
    for (int i = tid; i < 128 * 48; i += 256) {
        int r = i / 48, c = i % 48;
        rws[r * 52 + c] = f2bf(relW[(size_t)(h * NTOK + qbase + r) * GRD + c]);
    }
    for (int i = tid; i < 128 * 12; i += 256) {
        int r = i / 12, c = i % 12;
        rhs[r * 14 + c] = f2bf(relH[(size_t)(h * NTOK + qbase + r) * GRD + chunk * 12 + c]);
    }
    bf16x8 qf[2][2];
    #pragma unroll
    for (int s = 0; s < 2; s++) {
        int qrow = qbase + wave * 32 + s * 16 + l16;
        qf[s][0] = *(const bf16x8*)&Qb[(size_t)(h * NTOK + qrow) * HD + quad * 8];
        qf[s][1] = *(const bf16x8*)&Qb[(size_t)(h * NTOK + qrow) * HD + 32 + quad * 8];
    }
    int r0 = tid >> 3, c0 = (tid & 7) * 8;
    const ushort_t* kg0 = Kb + (size_t)(h * NTOK + r0) * HD + c0;
    const ushort_t* kg1 = Kb + (size_t)(h * NTOK + r0 + 32) * HD + c0;
    const ushort_t* vg0 = Vtb + (size_t)(h * HD + r0) * NTOK + c0;
    const ushort_t* vg1 = Vtb + (size_t)(h * HD + r0 + 32) * NTOK + c0;
    int sk0 = r0 * 68 + c0, sk1 = sk0 + 32 * 68;
    float lacc[2] = {0.f, 0.f};
    f32x4 zero = {0.f, 0.f, 0.f, 0.f};
    f32x4 oacc[2][4];
    #pragma unroll
    for (int s = 0; s < 2; s++)
        #pragma unroll
        for (int cs = 0; cs < 4; cs++) oacc[s][cs] = zero;
    const float scale2 = 0.125f * LOG2E;
    uint4 rk0 = *(const uint4*)(kg0 + (size_t)kbase * HD);
    uint4 rk1 = *(const uint4*)(kg1 + (size_t)kbase * HD);
    uint4 rv0 = *(const uint4*)(vg0 + kbase);
    uint4 rv1 = *(const uint4*)(vg1 + kbase);
    for (int kt = 0; kt < 9; kt++) {
        int kb = kbase + kt * 64;
        __syncthreads();
        *(uint4*)&Ks[sk0] = rk0;  *(uint4*)&Ks[sk1] = rk1;
        *(uint4*)&Vs[sk0] = rv0;  *(uint4*)&Vs[sk1] = rv1;
        __syncthreads();
        if (kt < 8) {
            int kbn = kb + 64;
            rk0 = *(const uint4*)(kg0 + (size_t)kbn * HD);
            rk1 = *(const uint4*)(kg1 + (size_t)kbn * HD);
            rv0 = *(const uint4*)(vg0 + kbn);
            rv1 = *(const uint4*)(vg1 + kbn);
        }
        #pragma unroll
        for (int ks = 0; ks < 4; ks++) {
            bf16x8 kf0 = *(const bf16x8*)&Ks[(ks * 16 + l16) * 68 + quad * 8];
            bf16x8 kf1 = *(const bf16x8*)&Ks[(ks * 16 + l16) * 68 + 32 + quad * 8];
            f32x4 st[2];
            #pragma unroll
            for (int s = 0; s < 2; s++) {
                f32x4 z = zero;
                z = __builtin_amdgcn_mfma_f32_16x16x32_bf16(kf0, qf[s][0], z, 0, 0, 0);
                z = __builtin_amdgcn_mfma_f32_16x16x32_bf16(kf1, qf[s][1], z, 0, 0, 0);
                st[s] = z;
            }
            int kb4 = kb + ks * 16 + quad * 4;
            int kh = kb4 / 48;
            int khl = kh - chunk * 12;
            int kw0 = kb4 - kh * 48;
            #pragma unroll
            for (int s = 0; s < 2; s++) {
                int row = wave * 32 + s * 16 + l16;
                float rh = bf2f(rhs[row * 14 + khl]);
                uint2 u = *(const uint2*)&rws[row * 52 + kw0];
                float p0 = __builtin_amdgcn_exp2f(st[s][0] * scale2 + rh + __uint_as_float(u.x << 16));
                float p1 = __builtin_amdgcn_exp2f(st[s][1] * scale2 + rh + __uint_as_float(u.x & 0xffff0000u));
                float p2 = __builtin_amdgcn_exp2f(st[s][2] * scale2 + rh + __uint_as_float(u.y << 16));
                float p3 = __builtin_amdgcn_exp2f(st[s][3] * scale2 + rh + __uint_as_float(u.y & 0xffff0000u));
                lacc[s] += (p0 + p1) + (p2 + p3);
                uint2 w;
                w.x = __builtin_amdgcn_perm(__float_as_uint(p1), __float_as_uint(p0), 0x07060302u);
                w.y = __builtin_amdgcn_perm(__float_as_uint(p3), __float_as_uint(p2), 0x07060302u);
                *(uint2*)&Ps[wave][(s * 16 + l16) * 68 + ks * 16 + quad * 4] = w;
            }
        }
        bf16x8 vf[4][2];
        #pragma unroll
        for (int cs = 0; cs < 4; cs++) {
            vf[cs][0] = *(const bf16x8*)&Vs[(cs * 16 + l16) * 68 + quad * 8];
            vf[cs][1] = *(const bf16x8*)&Vs[(cs * 16 + l16) * 68 + 32 + quad * 8];
        }
        #pragma unroll
        for (int s = 0; s < 2; s++) {
            bf16x8 pa0 = *(const bf16x8*)&Ps[wave][(s * 16 + l16) * 68 + quad * 8];
            bf16x8 pa1 = *(const bf16x8*)&Ps[wave][(s * 16 + l16) * 68 + 32 + quad * 8];
            #pragma unroll
            for (int cs = 0; cs < 4; cs++) {
                oacc[s][cs] = __builtin_amdgcn_mfma_f32_16x16x32_bf16(pa0, vf[cs][0], oacc[s][cs], 0, 0, 0);
                oacc[s][cs] = __builtin_amdgcn_mfma_f32_16x16x32_bf16(pa1, vf[cs][1], oacc[s][cs], 0, 0, 0);
            }
        }
    }
    #pragma unroll
    for (int s = 0; s < 2; s++) {
        float l = lacc[s];
        l += __shfl_xor(l, 16);
        l += __shfl_xor(l, 32);
        lacc[s] = l;
    }
    size_t obase = (size_t)(chunk * HEADS + h) * NTOK;
    #pragma unroll
    for (int s = 0; s < 2; s++) {
        #pragma unroll
        for (int cs = 0; cs < 4; cs++) {
            #pragma unroll
            for (int r = 0; r < 4; r++) {
                int row = qbase + wave * 32 + s * 16 + quad * 4 + r;
                Opart[(obase + row) * HD + cs * 16 + l16] = oacc[s][cs][r];
            }
        }
        if (quad == 0)
            Lpart[obase + qbase + wave * 32 + s * 16 + l16] = lacc[s];
    }
}

__global__ __launch_bounds__(256) void k_merge(const float* __restrict__ Opart,
                                               const float* __restrict__ Lpart,
                                               ushort_t* __restrict__ Ob) {
    int t = blockIdx.x * 256 + threadIdx.x;
    int e = t * 4;
    int c = e & (HD - 1);
    int row = (e >> 6) % NTOK;
    int h = e / (NTOK * HD);
    const int ostride = HEADS * NTOK * HD;
    float4 s = {0.f, 0.f, 0.f, 0.f};
    float l = 0.f;
    #pragma unroll
    for (int ch = 0; ch < CHUNKS; ch++) {
        float4 v = *(const float4*)&Opart[(size_t)ch * ostride + e];
        s.x += v.x; s.y += v.y; s.z += v.z; s.w += v.w;
        l += Lpart[(size_t)(ch * HEADS + h) * NTOK + row];
    }
    float inv = 1.0f / l;
    ushort4 o = make_ushort4(f2bf(s.x * inv), f2bf(s.y * inv),
                             f2bf(s.z * inv), f2bf(s.w * inv));
    *(ushort4*)&Ob[(size_t)row * DIM + h * HD + c] = o;
}

__global__ __launch_bounds__(256) void k_gemm_proj(
    const ushort_t* __restrict__ Ob, const ushort_t* __restrict__ WTp,
    const float* __restrict__ bp, float* __restrict__ out) {
    __shared__ __align__(16) ushort_t As[128 * 40];
    __shared__ __align__(16) ushort_t Bs[128 * 40];
    int tid = threadIdx.x;
    int wave = tid >> 6, lane = tid & 63, quad = lane >> 4, l16 = lane & 15;
    int wx = wave & 1, wy = wave >> 1;
    int nb = blockIdx.x * 128, mb = blockIdx.y * 128;
    f32x4 zero = {0.f, 0.f, 0.f, 0.f};
    f32x4 acc[4][4];
    #pragma unroll
    for (int i = 0; i < 4; i++)
        #pragma unroll
        for (int j = 0; j < 4; j++) acc[i][j] = zero;
    const ushort_t* Ag = Ob + (size_t)(mb + (tid >> 1)) * DIM + (tid & 1) * 16;
    const ushort_t* Bg = WTp + (size_t)(nb + (tid >> 1)) * DIM + (tid & 1) * 16;
    int sidx = (tid >> 1) * 40 + (tid & 1) * 16;
    for (int k0 = 0; k0 < DIM; k0 += 32) {
        uint4 a0 = *(const uint4*)(Ag + k0);
        uint4 a1 = *(const uint4*)(Ag + k0 + 8);
        uint4 b0 = *(const uint4*)(Bg + k0);
        uint4 b1 = *(const uint4*)(Bg + k0 + 8);
        __syncthreads();
        *(uint4*)&As[sidx] = a0;  *(uint4*)&As[sidx + 8] = a1;
        *(uint4*)&Bs[sidx] = b0;  *(uint4*)&Bs[sidx + 8] = b1;
        __syncthreads();
        bf16x8 af[4], bf[4];
        #pragma unroll
        for (int i = 0; i < 4; i++)
            af[i] = *(const bf16x8*)&As[(wy * 64 + i * 16 + l16) * 40 + quad * 8];
        #pragma unroll
        for (int j = 0; j < 4; j++)
            bf[j] = *(const bf16x8*)&Bs[(wx * 64 + j * 16 + l16) * 40 + quad * 8];
        #pragma unroll
        for (int i = 0; i < 4; i++)
            #pragma unroll
            for (int j = 0; j < 4; j++)
                acc[i][j] = __builtin_amdgcn_mfma_f32_16x16x32_bf16(af[i], bf[j], acc[i][j], 0, 0, 0);
    }
    #pragma unroll
    for (int j = 0; j < 4; j++) {
        int col = nb + wx * 64 + j * 16 + l16;
        float bval = bp[col];
        #pragma unroll
        for (int i = 0; i < 4; i++) {
            #pragma unroll
            for (int r = 0; r < 4; r++) {
                int row = mb + wy * 64 + i * 16 + quad * 4 + r;
                out[(size_t)row * DIM + col] = acc[i][j][r] + bval;
            }
        }
    }
}

// ---------------------------------------------------------------------------
extern "C" void kernel_launch(void* const* d_in, const int* in_sizes, int n_in,
                              void* d_out, int out_size, void* d_ws, size_t ws_size,
                              hipStream_t stream) {
    const float* x   = (const float*)d_in[0];
    const float* Wq  = (const float*)d_in[1];
    const float* bq  = (const float*)d_in[2];
    const float* Wk  = (const float*)d_in[3];
    const float* bk  = (const float*)d_in[4];
    const float* Wv  = (const float*)d_in[5];
    const float* bv  = (const float*)d_in[6];
    const float* Wp  = (const float*)d_in[7];
    const float* bp  = (const float*)d_in[8];
    const float* rph = (const float*)d_in[9];
    const float* rpw = (const float*)d_in[10];
    const float* Aq  = (const float*)d_in[11];
    const float* Bq  = (const float*)d_in[12];
    const float* Ak  = (const float*)d_in[13];
    const float* Bk  = (const float*)d_in[14];
    const float* Av  = (const float*)d_in[15];
    const float* Bv  = (const float*)d_in[16];
    float* out = (float*)d_out;

    char* w = (char*)d_ws;
    size_t off = 0;
    auto carve = [&](size_t bytes) {
        char* p = w + off;
        off += (bytes + 255) & ~(size_t)255;
        return p;
    };
    ushort_t* xb    = (ushort_t*)carve((size_t)NTOK * DIM * 2);
    ushort_t* WT    = (ushort_t*)carve((size_t)4 * DIM * DIM * 2);
    ushort_t* Qb    = (ushort_t*)carve((size_t)HEADS * NTOK * HD * 2);
    ushort_t* Kb    = (ushort_t*)carve((size_t)HEADS * NTOK * HD * 2);
    ushort_t* Vtb   = (ushort_t*)carve((size_t)HEADS * HD * NTOK * 2);
    float*    relH  = (float*)carve((size_t)HEADS * NTOK * GRD * 4);
    float*    relW  = (float*)carve((size_t)HEADS * NTOK * GRD * 4);
    ushort_t* Ob    = (ushort_t*)carve((size_t)NTOK * DIM * 2);
    float*    Opart = (float*)carve((size_t)CHUNKS * HEADS * NTOK * HD * 4);
    float*    Lpart = (float*)carve((size_t)CHUNKS * HEADS * NTOK * 4);
    ushort_t* rphb  = (ushort_t*)carve((size_t)(2 * GRD - 1) * HD * 2);
    ushort_t* rpwb  = (ushort_t*)carve((size_t)(2 * GRD - 1) * HD * 2);

    // capability check (host-side, graph-capture-safe)
    int coop = 0, dev = 0, maxblk = 0;
    hipGetDevice(&dev);
    hipDeviceGetAttribute(&coop, hipDeviceAttributeCooperativeLaunch, dev);
    hipOccupancyMaxActiveBlocksPerMultiprocessor(&maxblk, (const void*)k_mono, 256, 0);

    if (coop && maxblk >= 3) {
        MonoP P;
        P.x = x; P.Wq = Wq; P.bq = bq; P.Wk = Wk; P.bk = bk; P.Wv = Wv; P.bv = bv;
        P.Wp = Wp; P.bp = bp; P.rph = rph; P.rpw = rpw;
        P.Aq = Aq; P.Bq = Bq; P.Ak = Ak; P.Bk = Bk; P.Av = Av; P.Bv = Bv;
        P.out = out;
        P.xb = xb; P.WT = WT; P.Qb = Qb; P.Kb = Kb; P.Vtb = Vtb; P.Ob = Ob;
        P.rphb = rphb; P.rpwb = rpwb;
        P.relH = relH; P.relW = relW; P.Opart = Opart; P.Lpart = Lpart;
        void* args[] = { (void*)&P };
        hipLaunchCooperativeKernel((const void*)k_mono, dim3(NBLK), dim3(256),
                                   args, 0, stream);
    } else {
        k_convert_x<<<dim3(1728 + 12), dim3(256), 0, stream>>>(x, xb, rph, rpw, rphb, rpwb);
        k_fold<<<dim3(DIM / 32, 4 * DIM / 32), dim3(256), 0, stream>>>(
            Wq, Wk, Wv, Wp, Aq, Bq, Ak, Bk, Av, Bv, WT);
        k_gemm_qkv<<<dim3(18, 18), dim3(256), 0, stream>>>(
            xb, WT, bq, bk, bv, Qb, Kb, Vtb);
        k_relmm<<<dim3(288), dim3(256), 0, stream>>>(
            Qb, rphb, rpwb, relH, relW);
        k_attn<<<dim3(HEADS * CHUNKS, NTOK / 128), dim3(256), 0, stream>>>(
            Qb, Kb, Vtb, relH, relW, Opart, Lpart);
        k_merge<<<dim3(HEADS * NTOK * HD / (256 * 4)), dim3(256), 0, stream>>>(
            Opart, Lpart, Ob);
        k_gemm_proj<<<dim3(6, 18), dim3(256), 0, stream>>>(
            Ob, WT + (size_t)3 * DIM * DIM, bp, out);
    }
}